// Round 5
// baseline (548.042 us; speedup 1.0000x reference)
//
#include <hip/hip_runtime.h>
#include <math.h>

#define BB 256
#define TT 512
#define KK 128
#define AIDX(i) ((i) + (((i) >> 5) << 2))

typedef float v2f __attribute__((ext_vector_type(2)));

template<int CTRL>
__device__ __forceinline__ int dpp_i(int x) {
  return __builtin_amdgcn_update_dpp(x, x, CTRL, 0xF, 0xF, true);
}
template<int CTRL>
__device__ __forceinline__ float dpp_f(float x) {
  return __int_as_float(dpp_i<CTRL>(__float_as_int(x)));
}
template<int CTRL>
__device__ __forceinline__ v2f dpp_v2(v2f x) {
  v2f r; r.x = dpp_f<CTRL>(x.x); r.y = dpp_f<CTRL>(x.y); return r;
}
__device__ __forceinline__ float swz_f(float x, int imm) { return x; } // unused
__device__ __forceinline__ float swz8_f(float x) {
  return __int_as_float(__builtin_amdgcn_ds_swizzle(__float_as_int(x), 0x201F));
}
__device__ __forceinline__ float swz16_f(float x) {
  return __int_as_float(__builtin_amdgcn_ds_swizzle(__float_as_int(x), 0x401F));
}
// barrier draining LDS only — global prefetch/stores stay in flight
#define BARRIER_LGKM() asm volatile("s_waitcnt lgkmcnt(0)\ns_barrier" ::: "memory")

// DPP: 0xB1 quad_perm xor1, 0x4E quad_perm xor2,
// 0x141 row_half_mirror (==xor4 once quad-uniform)

__global__ __launch_bounds__(512, 2) void crf_fused(
    const float* __restrict__ logits,     // [B,T,K]
    const int* __restrict__ labels,       // [B,T]
    const int* __restrict__ seq_lens,     // [B]
    const float* __restrict__ trans,      // [K,K]
    float* __restrict__ pred_out,         // [B,T] as float (d_out+1)
    float* __restrict__ negll,            // [B] in ws
    float* __restrict__ ahist)            // [B,T,K] exact viterbi alphas in ws
{
  const int b = blockIdx.x;
  const int tid = threadIdx.x;
  const int half = tid >> 8;            // 0 = viterbi, 1 = forward
  const int ht = tid & 255;
  const int cg = ht >> 3, rg = ht & 7;
  const int j0 = cg * 4, i0 = rg * 16;
  const int L = seq_lens[b];

  __shared__ __align__(16) float av[2][144];
  __shared__ __align__(16) float ev[2][144];
  __shared__ __align__(16) float wmaxA[8];
  __shared__ __align__(16) float transT[KK * 132];   // 67584 B, staged post-loop
  __shared__ unsigned char tags[TT];
  __shared__ float rv[4]; __shared__ int ri[4];
  __shared__ float rs[8]; __shared__ float rsc[8];
  __shared__ int last_s;

  // transition regs: rows i0..i0+15, cols j0..j0+3 (V raw, F exp)
  float4 tq[16];
#pragma unroll
  for (int ii = 0; ii < 16; ++ii) {
    float4 tr = *(const float4*)&trans[(i0 + ii) * KK + j0];
    if (half == 0) tq[ii] = tr;
    else tq[ii] = make_float4(__expf(tr.x), __expf(tr.y), __expf(tr.z), __expf(tr.w));
  }

  if (half == 0 && ht < KK) {
    float l0 = logits[(size_t)(b * TT) * KK + ht];
    av[0][AIDX(ht)] = l0;
    ahist[(size_t)(b * TT) * KK + ht] = l0;
  }
  if (half == 1 && ht < KK)
    ev[0][AIDX(ht)] = __expf(logits[(size_t)(b * TT) * KK + ht]);
  if (half == 1 && (ht & 31) == 0) wmaxA[ht >> 5] = 1.0f;

  float4 emC[4], emN[4];
#pragma unroll
  for (int s = 0; s < 4; ++s) {
    int t2 = 1 + s; if (t2 > L - 1) t2 = (L > 1) ? (L - 1) : 0;
    emC[s] = *(const float4*)&logits[((size_t)b * TT + t2) * KK + j0];
  }
  __syncthreads();

  float Cln = 0.0f;
  for (int tc = 1; tc < L; tc += 4) {
#pragma unroll
    for (int s = 0; s < 4; ++s) {
      int t2 = tc + 4 + s; if (t2 > L - 1) t2 = L - 1;
      emN[s] = *(const float4*)&logits[((size_t)b * TT + t2) * KK + j0];
    }
    float r = 1.0f;
    if (half == 1) {        // renorm factor from previous chunk's wmax (exact pow2)
      float4 w0 = *(const float4*)&wmaxA[0];
      float4 w1 = *(const float4*)&wmaxA[4];
      float U = fmaxf(fmaxf(fmaxf(w0.x, w0.y), fmaxf(w0.z, w0.w)),
                      fmaxf(fmaxf(w1.x, w1.y), fmaxf(w1.z, w1.w)));
      int ex = (__float_as_int(U) >> 23) & 255;
      r = __int_as_float((254 - ex) << 23);
      Cln += (float)(ex - 127) * 0.6931471805599453f;
    }
#pragma unroll
    for (int s = 0; s < 4; ++s) {
      const int t = tc + s;
      if (t >= L) break;                 // uniform across block
      const int rd = (t & 1) ^ 1, wr = t & 1;
      float4 em4 = emC[s];

      if (half == 0) {
        // ---- VITERBI: max over 16 rows x 4 cols, NO index computation ----
        const float4* avr = (const float4*)(av[rd] + AIDX(i0));
        v2f accA[4], accB[4];
#pragma unroll
        for (int q = 0; q < 4; ++q) {
          float4 a4 = avr[q];
#pragma unroll
          for (int c = 0; c < 4; ++c) {
            float a = (c == 0) ? a4.x : (c == 1) ? a4.y : (c == 2) ? a4.z : a4.w;
            float4 tr = tq[q * 4 + c];
            v2f lo = (v2f){a + tr.x, a + tr.y};   // exact IEEE adds
            v2f hi = (v2f){a + tr.z, a + tr.w};
            if (q == 0) { accA[c] = lo; accB[c] = hi; }
            else {
              accA[c] = __builtin_elementwise_max(accA[c], lo);
              accB[c] = __builtin_elementwise_max(accB[c], hi);
            }
          }
        }
        v2f mA = __builtin_elementwise_max(
            __builtin_elementwise_max(accA[0], accA[1]),
            __builtin_elementwise_max(accA[2], accA[3]));
        v2f mB = __builtin_elementwise_max(
            __builtin_elementwise_max(accB[0], accB[1]),
            __builtin_elementwise_max(accB[2], accB[3]));
        mA = __builtin_elementwise_max(mA, dpp_v2<0xB1>(mA));
        mB = __builtin_elementwise_max(mB, dpp_v2<0xB1>(mB));
        mA = __builtin_elementwise_max(mA, dpp_v2<0x4E>(mA));
        mB = __builtin_elementwise_max(mB, dpp_v2<0x4E>(mB));
        mA = __builtin_elementwise_max(mA, dpp_v2<0x141>(mA));
        mB = __builtin_elementwise_max(mB, dpp_v2<0x141>(mB));
        v2f nA = mA + (v2f){em4.x, em4.y};
        v2f nB = mB + (v2f){em4.z, em4.w};
        if (rg == 0) {
          float4 o = make_float4(nA.x, nA.y, nB.x, nB.y);
          *(float4*)(av[wr] + AIDX(j0)) = o;
          *(float4*)&ahist[((size_t)b * TT + t) * KK + j0] = o;   // exact history
        }
      } else {
        // ---- FORWARD: linear-domain matvec ----
        const float4* evr = (const float4*)(ev[rd] + AIDX(i0));
        v2f SA = {0.0f, 0.0f}, SB = {0.0f, 0.0f};
#pragma unroll
        for (int q = 0; q < 4; ++q) {
          float4 e4 = evr[q];
#pragma unroll
          for (int c = 0; c < 4; ++c) {
            float e = (c == 0) ? e4.x : (c == 1) ? e4.y : (c == 2) ? e4.z : e4.w;
            float4 tw = tq[q * 4 + c];
            SA += (v2f){e, e} * (v2f){tw.x, tw.y};
            SB += (v2f){e, e} * (v2f){tw.z, tw.w};
          }
        }
        SA += dpp_v2<0xB1>(SA); SB += dpp_v2<0xB1>(SB);
        SA += dpp_v2<0x4E>(SA); SB += dpp_v2<0x4E>(SB);
        SA += dpp_v2<0x141>(SA); SB += dpp_v2<0x141>(SB);
        v2f uA = SA * (v2f){__expf(em4.x), __expf(em4.y)};
        v2f uB = SB * (v2f){__expf(em4.z), __expf(em4.w)};
        if (s == 0) { uA *= (v2f){r, r}; uB *= (v2f){r, r}; }
        if (rg == 0)
          *(float4*)(ev[wr] + AIDX(j0)) = make_float4(uA.x, uA.y, uB.x, uB.y);
        if (s == 3) {
          float wm = fmaxf(fmaxf(uA.x, uA.y), fmaxf(uB.x, uB.y));
          wm = fmaxf(wm, swz8_f(wm));    // xor8  (cg bit 0)
          wm = fmaxf(wm, swz16_f(wm));   // xor16 (cg bit 1)
          if ((ht & 31) == 0) wmaxA[ht >> 5] = wm;  // per half-wave entry
        }
      }
      BARRIER_LGKM();
    }
#pragma unroll
    for (int s = 0; s < 4; ++s) emC[s] = emN[s];
  }

  // ---- stage trans^T into LDS for backtrace ----
  for (int idx = tid; idx < KK * KK; idx += 512) {
    int i = idx >> 7, j = idx & 127;
    transT[j * 132 + i] = trans[idx];    // coalesced global read
  }

  const float* avf = av[(L - 1) & 1];
  const float* evf = ev[(L - 1) & 1];
  if (half == 0) {
    float v = (ht < KK) ? avf[AIDX(ht)] : -3.4e38f;
    int idx = (ht < KK) ? ht : KK;
#pragma unroll
    for (int mm = 1; mm < 64; mm <<= 1) {
      float ov = __shfl_xor(v, mm);
      int oi = __shfl_xor(idx, mm);
      if (ov > v || (ov == v && oi < idx)) { v = ov; idx = oi; }
    }
    if ((tid & 63) == 0) { rv[tid >> 6] = v; ri[tid >> 6] = idx; }
  } else {
    float ssum = (ht < KK) ? evf[AIDX(ht)] : 0.0f;
#pragma unroll
    for (int mm = 1; mm < 64; mm <<= 1) ssum += __shfl_xor(ssum, mm);
    if ((tid & 63) == 0) rs[tid >> 6] = ssum;
    float sc = 0.0f;
    for (int tt2 = ht; tt2 < L; tt2 += 256) {
      int lab = labels[b * TT + tt2];
      sc += logits[((size_t)b * TT + tt2) * KK + lab];
      if (tt2 >= 1) sc += trans[labels[b * TT + tt2 - 1] * KK + lab];
    }
#pragma unroll
    for (int mm = 1; mm < 64; mm <<= 1) sc += __shfl_xor(sc, mm);
    if ((tid & 63) == 0) rsc[tid >> 6] = sc;
  }
  __syncthreads();

  if (tid == 0) {
    float bv = rv[0]; int bi = ri[0];
#pragma unroll
    for (int w = 1; w < 4; ++w)
      if (rv[w] > bv || (rv[w] == bv && ri[w] < bi)) { bv = rv[w]; bi = ri[w]; }
    last_s = bi;
  }
  if (tid == 256) {
    float es = rs[4] + rs[5] + rs[6] + rs[7];
    float scf = rsc[4] + rsc[5] + rsc[6] + rsc[7];
    negll[b] = (Cln + logf(es)) - scf;
  }
  __syncthreads();
  const int last = last_s;
  if (tid >= L - 1) tags[tid] = (unsigned char)last;
  __syncthreads();

  // ---- backtrace (wave 0): recompute path argmaxes from exact alphas ----
  if (tid < 64 && L >= 2) {
    const int lane = tid;
    int tag = last;
    int t = L - 1;
    while (t >= 1) {
      int n = (t < 4) ? t : 4;
      float2 rows[4];
#pragma unroll
      for (int k = 0; k < 4; ++k)
        if (k < n)
          rows[k] = *(const float2*)&ahist[((size_t)b * TT + (t - 1 - k)) * KK + lane * 2];
#pragma unroll
      for (int k = 0; k < 4; ++k) {
        if (k < n) {
          float2 trow = *(const float2*)&transT[tag * 132 + lane * 2];
          float qx = rows[k].x + trow.x;     // bitwise == forward's scores
          float qy = rows[k].y + trow.y;
          float M = fmaxf(qx, qy);
#pragma unroll
          for (int mm = 1; mm < 64; mm <<= 1) M = fmaxf(M, __shfl_xor(M, mm));
          unsigned long long bx = __ballot(qx == M);
          unsigned long long by = __ballot(qy == M);
          int ix = bx ? (__ffsll((unsigned long long)bx) - 1) * 2 : 1 << 20;
          int iy = by ? (__ffsll((unsigned long long)by) - 1) * 2 + 1 : 1 << 20;
          tag = (ix < iy) ? ix : iy;        // first-index tie-break, exact
          if (lane == 0) tags[t - 1 - k] = (unsigned char)tag;
        }
      }
      t -= n;
    }
  }
  __syncthreads();
  pred_out[(size_t)b * TT + tid] = (float)tags[tid];
}

__global__ void crf_loss_reduce(const float* __restrict__ negll, float* __restrict__ out) {
  int tid = threadIdx.x;
  float v = negll[tid];
#pragma unroll
  for (int m = 1; m < 64; m <<= 1) v += __shfl_xor(v, m);
  __shared__ float p[4];
  if ((tid & 63) == 0) p[tid >> 6] = v;
  __syncthreads();
  if (tid == 0) out[0] = p[0] + p[1] + p[2] + p[3];
}

extern "C" void kernel_launch(void* const* d_in, const int* in_sizes, int n_in,
                              void* d_out, int out_size, void* d_ws, size_t ws_size,
                              hipStream_t stream) {
  const float* logits   = (const float*)d_in[0];
  const int*   labels   = (const int*)d_in[1];
  const int*   seq_lens = (const int*)d_in[2];
  const float* trans    = (const float*)d_in[3];
  float* out = (float*)d_out;

  float* negll = (float*)d_ws;                      // 256 floats
  float* ahist = (float*)((char*)d_ws + 1024);      // B*T*K fp32 = 67.1 MB

  crf_fused<<<BB, 512, 0, stream>>>(logits, labels, seq_lens, trans,
                                    out + 1, negll, ahist);
  crf_loss_reduce<<<1, 256, 0, stream>>>(negll, out);
}